// Round 6
// baseline (99.858 us; speedup 1.0000x reference)
//
#include <hip/hip_runtime.h>

namespace {

constexpr int F_FEAT = 310;
constexpr int KDIM   = 309;
constexpr int BSZ    = 2048;
constexpr int HDIM   = 32;
constexpr int NCH    = 10;          // K chunks of 32 (309 -> 320, zero-padded in W1T)
constexpr int NX     = F_FEAT * BSZ;

// workspace layout
constexpr int    NBLK8    = NX / 8 + 2;               // 79362 16B blocks per x copy
constexpr size_t CSTR_B   = (size_t)NBLK8 * 16;       // bytes per x copy
constexpr size_t XC_BYTES = CSTR_B * 8;               // 8 shift copies
constexpr size_t W1T_FSTR = 32 * 320 * 2;             // [32 h][320 k] bf16
constexpr size_t W1T_OFF  = XC_BYTES;
constexpr size_t W2T_OFF  = W1T_OFF + (size_t)F_FEAT * W1T_FSTR;
constexpr size_t WT_FSTR  = 32 * 32 * 2;
constexpr size_t W3T_OFF  = W2T_OFF + (size_t)F_FEAT * WT_FSTR;
constexpr size_t WS_NEED  = W3T_OFF + (size_t)F_FEAT * WT_FSTR;

constexpr int NBX      = (NBLK8 + 255) / 256;         // 311 blocks per copy
constexpr int CVT_XBLK = NBX * 8;                     // 2488 x-role blocks
constexpr int CVT_BLK  = CVT_XBLK + F_FEAT * 6;       // + 1860 w-role blocks

typedef __bf16 bf16x8 __attribute__((ext_vector_type(8)));
typedef float  f32x4  __attribute__((ext_vector_type(4)));

#define MFMA(a, b, c) __builtin_amdgcn_mfma_f32_16x16x32_bf16((a), (b), (c), 0, 0, 0)

// ---------- one fused conversion pass ----------
// x-role: x -> 8 shift-aligned bf16 copies (copy c holds element i at position i+c).
// w-role: W1 -> bf16 [h][320k] (k>=309 zero); W2/W3 -> bf16 [h][k].
__global__ __launch_bounds__(256) void cvt_all(
    const float* __restrict__ x,  const float* __restrict__ W1,
    const float* __restrict__ W2, const float* __restrict__ W3,
    char* __restrict__ ws)
{
    __shared__ float tile[64][33];
    const int b = blockIdx.x, tid = threadIdx.x;

    if (b < CVT_XBLK) {
        const int c = b / NBX, mb = b - c * NBX;
        const int m = mb * 256 + tid;
        if (m >= NBLK8) return;
        const int e0 = m * 8 - c;
        bf16x8 v;
        #pragma unroll
        for (int q = 0; q < 8; ++q) {
            const int i = e0 + q;
            v[q] = (__bf16)((i >= 0 && i < NX) ? x[i] : 0.f);
        }
        *(bf16x8*)(ws + (size_t)c * CSTR_B + (size_t)m * 16) = v;
        return;
    }

    const int wb = b - CVT_XBLK;
    const int fi = wb / 6, part = wb - fi * 6;

    if (part < 5) {   // W1 chunk-pair: 64k x 32h tile transpose (2048 elems = 256 thr x 8)
        const float* Wg = W1 + (size_t)fi * KDIM * HDIM;
        const int row = tid >> 2;            // 0..63
        const int c8  = (tid & 3) * 8;       // col group
        const int k   = part * 64 + row;
        float4 f0 = make_float4(0,0,0,0), f1 = f0;
        if (k < KDIM) {
            f0 = *(const float4*)&Wg[k * HDIM + c8];
            f1 = *(const float4*)&Wg[k * HDIM + c8 + 4];
        }
        tile[row][c8+0] = f0.x; tile[row][c8+1] = f0.y;
        tile[row][c8+2] = f0.z; tile[row][c8+3] = f0.w;
        tile[row][c8+4] = f1.x; tile[row][c8+5] = f1.y;
        tile[row][c8+6] = f1.z; tile[row][c8+7] = f1.w;
        __syncthreads();
        const int h = tid & 31, kq = (tid >> 5) * 8;   // kq 0..56 over 64 rows: OK here
        bf16x8 o;
        #pragma unroll
        for (int j = 0; j < 8; ++j) o[j] = (__bf16)tile[kq + j][h];
        *(bf16x8*)(ws + W1T_OFF + (size_t)fi * W1T_FSTR
                   + (size_t)(h * 320 + part * 64 + kq) * 2) = o;
    } else {          // W2 & W3: 32x32 transpose each (1024 elems = 128 thr x 8)
        const int kl = tid >> 3, h4 = (tid & 7) * 4;   // write roles (256 thr x 4)
        const int h = tid & 31, kq = (tid >> 5) * 8;   // read roles: valid only tid<128
        {
            const float* Wg = W2 + (size_t)fi * HDIM * HDIM;
            float4 f = *(const float4*)&Wg[kl * HDIM + h4];
            tile[kl][h4+0] = f.x; tile[kl][h4+1] = f.y;
            tile[kl][h4+2] = f.z; tile[kl][h4+3] = f.w;
            __syncthreads();
            if (tid < 128) {
                bf16x8 o;
                #pragma unroll
                for (int j = 0; j < 8; ++j) o[j] = (__bf16)tile[kq + j][h];
                *(bf16x8*)(ws + W2T_OFF + (size_t)fi * WT_FSTR + (size_t)(h * 32 + kq) * 2) = o;
            }
            __syncthreads();
        }
        {
            const float* Wg = W3 + (size_t)fi * HDIM * HDIM;
            float4 f = *(const float4*)&Wg[kl * HDIM + h4];
            tile[kl][h4+0] = f.x; tile[kl][h4+1] = f.y;
            tile[kl][h4+2] = f.z; tile[kl][h4+3] = f.w;
            __syncthreads();
            if (tid < 128) {
                bf16x8 o;
                #pragma unroll
                for (int j = 0; j < 8; ++j) o[j] = (__bf16)tile[kq + j][h];
                *(bf16x8*)(ws + W3T_OFF + (size_t)fi * WT_FSTR + (size_t)(h * 32 + kq) * 2) = o;
            }
        }
    }
}

// ---------- fused per-feature MLP: zero barriers, LDS only for h-transpose ----------
template<bool FAST>
__global__ __launch_bounds__(256, 8) void sfp2(
    const float* __restrict__ x,
    const float* __restrict__ W1, const float* __restrict__ b1,
    const float* __restrict__ W2, const float* __restrict__ b2,
    const float* __restrict__ W3, const float* __restrict__ b3,
    const char* __restrict__ ws, float* __restrict__ out)
{
    __shared__ __attribute__((aligned(16))) __bf16 h1s[128 * 40];   // 10240 B

    int fi, sb;
    if (FAST) {
        const int xc = blockIdx.x & 7, li = blockIdx.x >> 3;
        const int cnt = (xc < 6) ? 39 : 38;          // 310 = 6*39 + 2*38
        const int lf = li >> 4;
        if (lf >= cnt) return;
        fi = ((xc < 6) ? xc * 39 : 234 + (xc - 6) * 38) + lf;
        sb = li & 15;
    } else {
        fi = blockIdx.x >> 4; sb = blockIdx.x & 15;
    }

    const int tid = threadIdx.x, lane = tid & 63, wv = tid >> 6;
    const int l15 = lane & 15, l16 = lane >> 4;
    const int lk8 = l16 * 8, r0 = l16 * 4;
    const int b0 = sb << 7, iB = fi << 11;

    const float b1v0 = b1[fi*HDIM + l15], b1v1 = b1[fi*HDIM + 16 + l15];
    const float b2v0 = b2[fi*HDIM + l15], b2v1 = b2[fi*HDIM + 16 + l15];
    const float b3v0 = b3[fi*HDIM + l15], b3v1 = b3[fi*HDIM + 16 + l15];

    auto loadA = [&](int lin) -> bf16x8 {
        if (FAST) {
            if ((unsigned)(iB - 1 - lin) < 7u) {        // fragment straddles LOO cut
                bf16x8 r;
                #pragma unroll
                for (int q = 0; q < 8; ++q) {
                    int i = lin + q; i += (i >= iB) ? BSZ : 0;
                    r[q] = *(const __bf16*)(ws + (size_t)i * 2);   // copy 0
                }
                return r;
            }
            const int e  = lin + ((lin >= iB) ? BSZ : 0);
            const int c8 = (-e) & 7;
            return *(const bf16x8*)(ws + (size_t)c8 * CSTR_B + (size_t)(e + c8) * 2);
        } else {
            bf16x8 r;
            #pragma unroll
            for (int q = 0; q < 8; ++q) {
                int i = lin + q; i += (i >= iB) ? BSZ : 0;
                i = (i < NX) ? i : (NX - 1);
                r[q] = (__bf16)x[i];
            }
            return r;
        }
    };

    auto loadW1f = [&](int c, int hrow) -> bf16x8 {
        if (FAST) {
            return *(const bf16x8*)(ws + W1T_OFF + (size_t)fi * W1T_FSTR
                                    + (size_t)(hrow * 320 + c * 32 + lk8) * 2);
        } else {
            const float* Wg = W1 + (size_t)fi * KDIM * HDIM;
            bf16x8 r;
            #pragma unroll
            for (int q = 0; q < 8; ++q) {
                const int k = c * 32 + lk8 + q;
                r[q] = (__bf16)((k < KDIM) ? Wg[k * HDIM + hrow] : 0.f);
            }
            return r;
        }
    };

    // ---------------- layer 1: zero-barrier pipelined K-loop ----------------
    f32x4 acc00 = {0,0,0,0}, acc01 = {0,0,0,0}, acc10 = {0,0,0,0}, acc11 = {0,0,0,0};
    const int mrow = wv * 32;
    const int lin0 = (b0 + mrow + l15) * KDIM + lk8;
    const int lin1 = lin0 + 16 * KDIM;

    bf16x8 a0 = loadA(lin0),     a1 = loadA(lin1);
    bf16x8 w0 = loadW1f(0, l15), w1 = loadW1f(0, 16 + l15);
    for (int c = 0; c < NCH; ++c) {
        bf16x8 na0, na1, nw0, nw1;
        if (c + 1 < NCH) {
            na0 = loadA(lin0 + 32 * (c + 1));
            na1 = loadA(lin1 + 32 * (c + 1));
            nw0 = loadW1f(c + 1, l15);
            nw1 = loadW1f(c + 1, 16 + l15);
        }
        acc00 = MFMA(a0, w0, acc00);
        acc01 = MFMA(a0, w1, acc01);
        acc10 = MFMA(a1, w0, acc10);
        acc11 = MFMA(a1, w1, acc11);
        a0 = na0; a1 = na1; w0 = nw0; w1 = nw1;
    }

    // ---- bias+relu -> h1 (wave-local LDS transpose, no barrier) ----
    constexpr int LDA = 40;
    #pragma unroll
    for (int r = 0; r < 4; ++r) {
        float v;
        v = acc00[r] + b1v0; h1s[(mrow +      r0 + r)*LDA +      l15] = (__bf16)(v > 0.f ? v : 0.f);
        v = acc01[r] + b1v1; h1s[(mrow +      r0 + r)*LDA + 16 + l15] = (__bf16)(v > 0.f ? v : 0.f);
        v = acc10[r] + b1v0; h1s[(mrow + 16 + r0 + r)*LDA +      l15] = (__bf16)(v > 0.f ? v : 0.f);
        v = acc11[r] + b1v1; h1s[(mrow + 16 + r0 + r)*LDA + 16 + l15] = (__bf16)(v > 0.f ? v : 0.f);
    }

    auto loadW23 = [&](const float* Wg, size_t toff, int hrow) -> bf16x8 {
        if (FAST) {
            return *(const bf16x8*)(ws + toff + (size_t)fi * WT_FSTR
                                    + (size_t)(hrow * 32 + lk8) * 2);
        } else {
            bf16x8 r;
            #pragma unroll
            for (int q = 0; q < 8; ++q)
                r[q] = (__bf16)Wg[(size_t)fi * HDIM * HDIM + (lk8 + q) * HDIM + hrow];
            return r;
        }
    };

    // ---------------- layer 2 ----------------
    const f32x4 z = {0,0,0,0};
    f32x4 c200, c201, c210, c211;
    {
        bf16x8 ha0 = *(const bf16x8*)&h1s[(mrow +      l15)*LDA + lk8];
        bf16x8 ha1 = *(const bf16x8*)&h1s[(mrow + 16 + l15)*LDA + lk8];
        bf16x8 v0 = loadW23(W2, W2T_OFF, l15);
        bf16x8 v1 = loadW23(W2, W2T_OFF, 16 + l15);
        c200 = MFMA(ha0, v0, z); c201 = MFMA(ha0, v1, z);
        c210 = MFMA(ha1, v0, z); c211 = MFMA(ha1, v1, z);
    }
    #pragma unroll
    for (int r = 0; r < 4; ++r) {
        float v;
        v = c200[r] + b2v0; h1s[(mrow +      r0 + r)*LDA +      l15] = (__bf16)(v > 0.f ? v : 0.f);
        v = c201[r] + b2v1; h1s[(mrow +      r0 + r)*LDA + 16 + l15] = (__bf16)(v > 0.f ? v : 0.f);
        v = c210[r] + b2v0; h1s[(mrow + 16 + r0 + r)*LDA +      l15] = (__bf16)(v > 0.f ? v : 0.f);
        v = c211[r] + b2v1; h1s[(mrow + 16 + r0 + r)*LDA + 16 + l15] = (__bf16)(v > 0.f ? v : 0.f);
    }

    // ---------------- layer 3 ----------------
    f32x4 c300, c301, c310, c311;
    {
        bf16x8 ha0 = *(const bf16x8*)&h1s[(mrow +      l15)*LDA + lk8];
        bf16x8 ha1 = *(const bf16x8*)&h1s[(mrow + 16 + l15)*LDA + lk8];
        bf16x8 v0 = loadW23(W3, W3T_OFF, l15);
        bf16x8 v1 = loadW23(W3, W3T_OFF, 16 + l15);
        c300 = MFMA(ha0, v0, z); c301 = MFMA(ha0, v1, z);
        c310 = MFMA(ha1, v0, z); c311 = MFMA(ha1, v1, z);
    }

    // ---------------- output ----------------
    const size_t orow = (size_t)(fi * BSZ + b0 + mrow);
    #pragma unroll
    for (int r = 0; r < 4; ++r) {
        float v;
        v = c300[r] + b3v0; out[(orow +      r0 + r)*HDIM +      l15] = v > 0.f ? v : 0.f;
        v = c301[r] + b3v1; out[(orow +      r0 + r)*HDIM + 16 + l15] = v > 0.f ? v : 0.f;
        v = c310[r] + b3v0; out[(orow + 16 + r0 + r)*HDIM +      l15] = v > 0.f ? v : 0.f;
        v = c311[r] + b3v1; out[(orow + 16 + r0 + r)*HDIM + 16 + l15] = v > 0.f ? v : 0.f;
    }
}

} // namespace

extern "C" void kernel_launch(void* const* d_in, const int* in_sizes, int n_in,
                              void* d_out, int out_size, void* d_ws, size_t ws_size,
                              hipStream_t stream) {
    const float* x  = (const float*)d_in[0];
    const float* W1 = (const float*)d_in[1];
    const float* b1 = (const float*)d_in[2];
    const float* W2 = (const float*)d_in[3];
    const float* b2 = (const float*)d_in[4];
    const float* W3 = (const float*)d_in[5];
    const float* b3 = (const float*)d_in[6];
    float* out = (float*)d_out;
    char* ws = (char*)d_ws;

    const bool fast = (ws != nullptr) && (ws_size >= WS_NEED);
    if (fast) {
        hipLaunchKernelGGL(cvt_all, dim3(CVT_BLK), dim3(256), 0, stream, x, W1, W2, W3, ws);
        hipLaunchKernelGGL((sfp2<true>), dim3(8 * 39 * 16), dim3(256), 0, stream,
                           x, W1, b1, W2, b2, W3, b3, ws, out);
    } else {
        hipLaunchKernelGGL((sfp2<false>), dim3(F_FEAT * 16), dim3(256), 0, stream,
                           x, W1, b1, W2, b2, W3, b3, ws, out);
    }
}

// Round 7
// 70.927 us; speedup vs baseline: 1.4079x; 1.4079x over previous
//
#include <hip/hip_runtime.h>

namespace {

constexpr int F_FEAT = 310;
constexpr int KDIM   = 309;
constexpr int BSZ    = 2048;
constexpr int HDIM   = 32;
constexpr int NCH    = 10;          // K chunks of 32 (309 -> 320, zero-padded in W1T)
constexpr int NX     = F_FEAT * BSZ;

// workspace layout
constexpr int    NBLK8    = NX / 8 + 2;               // 79362 16B blocks per x copy
constexpr size_t CSTR_B   = (size_t)NBLK8 * 16;       // bytes per x copy
constexpr size_t XC_BYTES = CSTR_B * 8;               // 8 shift copies
constexpr size_t W1T_FSTR = 32 * 320 * 2;             // [32 h][320 k] bf16 (pre-swizzled)
constexpr size_t W1T_OFF  = XC_BYTES;
constexpr size_t W2T_OFF  = W1T_OFF + (size_t)F_FEAT * W1T_FSTR;
constexpr size_t WT_FSTR  = 32 * 32 * 2;
constexpr size_t W3T_OFF  = W2T_OFF + (size_t)F_FEAT * WT_FSTR;
constexpr size_t WS_NEED  = W3T_OFF + (size_t)F_FEAT * WT_FSTR;

constexpr int NBX      = (NBLK8 + 255) / 256;         // 311 blocks per copy
constexpr int CVT_XBLK = NBX * 8;                     // 2488 x-role blocks
constexpr int CVT_BLK  = CVT_XBLK + F_FEAT * 6;       // + 1860 w-role blocks

typedef __bf16 bf16x8 __attribute__((ext_vector_type(8)));
typedef float  f32x4  __attribute__((ext_vector_type(4)));

#define MFMA(a, b, c) __builtin_amdgcn_mfma_f32_16x16x32_bf16((a), (b), (c), 0, 0, 0)

// ---------- one fused conversion pass ----------
// x-role: x -> 8 shift-aligned bf16 copies (copy c holds element i at position i+c).
// w-role: W1 -> bf16 [h][320k], XOR-swizzled (byte ^= (h&7)<<4), k>=309 zero;
//         W2/W3 -> plain bf16 [h][k].
__global__ __launch_bounds__(256) void cvt_all(
    const float* __restrict__ x,  const float* __restrict__ W1,
    const float* __restrict__ W2, const float* __restrict__ W3,
    char* __restrict__ ws)
{
    __shared__ float tile[64][33];
    const int b = blockIdx.x, tid = threadIdx.x;

    if (b < CVT_XBLK) {
        const int c = b / NBX, mb = b - c * NBX;
        const int m = mb * 256 + tid;
        if (m >= NBLK8) return;
        const int e0 = m * 8 - c;
        bf16x8 v;
        #pragma unroll
        for (int q = 0; q < 8; ++q) {
            const int i = e0 + q;
            v[q] = (__bf16)((i >= 0 && i < NX) ? x[i] : 0.f);
        }
        *(bf16x8*)(ws + (size_t)c * CSTR_B + (size_t)m * 16) = v;
        return;
    }

    const int wb = b - CVT_XBLK;
    const int fi = wb / 6, part = wb - fi * 6;

    if (part < 5) {   // W1 chunk-pair: 64k x 32h tile transpose (2048 elems = 256 thr x 8)
        const float* Wg = W1 + (size_t)fi * KDIM * HDIM;
        const int row = tid >> 2;            // 0..63
        const int c8  = (tid & 3) * 8;       // col group
        const int k   = part * 64 + row;
        float4 f0 = make_float4(0,0,0,0), f1 = f0;
        if (k < KDIM) {
            f0 = *(const float4*)&Wg[k * HDIM + c8];
            f1 = *(const float4*)&Wg[k * HDIM + c8 + 4];
        }
        tile[row][c8+0] = f0.x; tile[row][c8+1] = f0.y;
        tile[row][c8+2] = f0.z; tile[row][c8+3] = f0.w;
        tile[row][c8+4] = f1.x; tile[row][c8+5] = f1.y;
        tile[row][c8+6] = f1.z; tile[row][c8+7] = f1.w;
        __syncthreads();
        const int h = tid & 31, kq = (tid >> 5) * 8;   // kq 0..56 over 64 rows
        bf16x8 o;
        #pragma unroll
        for (int j = 0; j < 8; ++j) o[j] = (__bf16)tile[kq + j][h];
        const int boff = (h * 640 + part * 128 + kq * 2) ^ ((h & 7) << 4);
        *(bf16x8*)(ws + W1T_OFF + (size_t)fi * W1T_FSTR + (size_t)boff) = o;
    } else {          // W2 & W3: 32x32 transpose each (1024 elems = 128 thr x 8)
        const int kl = tid >> 3, h4 = (tid & 7) * 4;   // write roles (256 thr x 4)
        const int h = tid & 31, kq = (tid >> 5) * 8;   // read roles: valid only tid<128
        {
            const float* Wg = W2 + (size_t)fi * HDIM * HDIM;
            float4 f = *(const float4*)&Wg[kl * HDIM + h4];
            tile[kl][h4+0] = f.x; tile[kl][h4+1] = f.y;
            tile[kl][h4+2] = f.z; tile[kl][h4+3] = f.w;
            __syncthreads();
            if (tid < 128) {
                bf16x8 o;
                #pragma unroll
                for (int j = 0; j < 8; ++j) o[j] = (__bf16)tile[kq + j][h];
                *(bf16x8*)(ws + W2T_OFF + (size_t)fi * WT_FSTR + (size_t)(h * 32 + kq) * 2) = o;
            }
            __syncthreads();
        }
        {
            const float* Wg = W3 + (size_t)fi * HDIM * HDIM;
            float4 f = *(const float4*)&Wg[kl * HDIM + h4];
            tile[kl][h4+0] = f.x; tile[kl][h4+1] = f.y;
            tile[kl][h4+2] = f.z; tile[kl][h4+3] = f.w;
            __syncthreads();
            if (tid < 128) {
                bf16x8 o;
                #pragma unroll
                for (int j = 0; j < 8; ++j) o[j] = (__bf16)tile[kq + j][h];
                *(bf16x8*)(ws + W3T_OFF + (size_t)fi * WT_FSTR + (size_t)(h * 32 + kq) * 2) = o;
            }
        }
    }
}

// ---------- fused per-feature MLP ----------
// W1T in LDS (swizzled, staged once, 1 barrier); A 2-deep reg pipeline from L2;
// hoisted per-row addressing (copy index constant per row since 2048 % 8 == 0).
template<bool FAST>
__global__ __launch_bounds__(256, 4) void sfp3(
    const float* __restrict__ x,
    const float* __restrict__ W1, const float* __restrict__ b1,
    const float* __restrict__ W2, const float* __restrict__ b2,
    const float* __restrict__ W3, const float* __restrict__ b3,
    const char* __restrict__ ws, float* __restrict__ out)
{
    __shared__ __attribute__((aligned(16))) __bf16 W1s[32 * 320];   // 20480 B
    __shared__ __attribute__((aligned(16))) __bf16 h1s[128 * 40];   // 10240 B

    int fi, sb;
    if (FAST) {
        const int xc = blockIdx.x & 7, li = blockIdx.x >> 3;
        const int cnt = (xc < 6) ? 39 : 38;          // 310 = 6*39 + 2*38
        const int lf = li >> 4;
        if (lf >= cnt) return;
        fi = ((xc < 6) ? xc * 39 : 234 + (xc - 6) * 38) + lf;
        sb = li & 15;
    } else {
        fi = blockIdx.x >> 4; sb = blockIdx.x & 15;
    }

    const int tid = threadIdx.x, lane = tid & 63, wv = tid >> 6;
    const int l15 = lane & 15, l16 = lane >> 4;
    const int lk8 = l16 * 8, r0 = l16 * 4;
    const int b0 = sb << 7, iB = fi << 11;

    if (FAST) {   // stage pre-swizzled W1T once (linear copy)
        const char* src = ws + W1T_OFF + (size_t)fi * W1T_FSTR;
        #pragma unroll
        for (int i = 0; i < 5; ++i) {
            const int off = i * 4096 + tid * 16;
            *(bf16x8*)((char*)W1s + off) = *(const bf16x8*)(src + off);
        }
        __syncthreads();
    }

    const float b1v0 = b1[fi*HDIM + l15], b1v1 = b1[fi*HDIM + 16 + l15];
    const float b2v0 = b2[fi*HDIM + l15], b2v1 = b2[fi*HDIM + 16 + l15];
    const float b3v0 = b3[fi*HDIM + l15], b3v1 = b3[fi*HDIM + 16 + l15];

    // hoisted W2/W3 fragments (L2 loads issued before the K-loop)
    bf16x8 w2a, w2b, w3a, w3b;
    if (FAST) {
        const char* p2 = ws + W2T_OFF + (size_t)fi * WT_FSTR;
        const char* p3 = ws + W3T_OFF + (size_t)fi * WT_FSTR;
        w2a = *(const bf16x8*)(p2 + (size_t)(l15 * 32 + lk8) * 2);
        w2b = *(const bf16x8*)(p2 + (size_t)((16 + l15) * 32 + lk8) * 2);
        w3a = *(const bf16x8*)(p3 + (size_t)(l15 * 32 + lk8) * 2);
        w3b = *(const bf16x8*)(p3 + (size_t)((16 + l15) * 32 + lk8) * 2);
    } else {
        #pragma unroll
        for (int q = 0; q < 8; ++q) {
            const size_t base = (size_t)fi * HDIM * HDIM + (lk8 + q) * HDIM;
            w2a[q] = (__bf16)W2[base + l15];      w2b[q] = (__bf16)W2[base + 16 + l15];
            w3a[q] = (__bf16)W3[base + l15];      w3b[q] = (__bf16)W3[base + 16 + l15];
        }
    }

    // ---------------- layer 1: per-row hoisted addressing ----------------
    const int mrow = wv * 32;
    const int lin0 = (b0 + mrow + l15) * KDIM + lk8;
    const int lin1 = lin0 + 16 * KDIM;
    const char* base0 = ws;
    const char* base1 = ws;
    if (FAST) {
        const int c80 = (-lin0) & 7, c81 = (-lin1) & 7;   // constant per row (2048%8==0)
        base0 = ws + (size_t)c80 * CSTR_B + (size_t)(lin0 + c80) * 2;
        base1 = ws + (size_t)c81 * CSTR_B + (size_t)(lin1 + c81) * 2;
    }

    auto fragA = [&](const char* base, int lin) -> bf16x8 {
        if (FAST) {
            if (__builtin_expect((unsigned)(iB - 1 - lin) < 7u, 0)) {  // straddles LOO cut
                bf16x8 r;
                #pragma unroll
                for (int q = 0; q < 8; ++q) {
                    int i = lin + q; i += (i >= iB) ? BSZ : 0;
                    r[q] = *(const __bf16*)(ws + (size_t)i * 2);       // copy 0
                }
                return r;
            }
            return *(const bf16x8*)(base + ((lin >= iB) ? 4096 : 0));
        } else {
            bf16x8 r;
            #pragma unroll
            for (int q = 0; q < 8; ++q) {
                int i = lin + q; i += (i >= iB) ? BSZ : 0;
                i = (i < NX) ? i : (NX - 1);
                r[q] = (__bf16)x[i];
            }
            return r;
        }
    };

    auto fragW1 = [&](int c, int hrow) -> bf16x8 {
        if (FAST) {
            const int boff = (hrow * 640 + c * 64 + l16 * 16) ^ ((hrow & 7) << 4);
            return *(const bf16x8*)((const char*)W1s + boff);
        } else {
            const float* Wg = W1 + (size_t)fi * KDIM * HDIM;
            bf16x8 r;
            #pragma unroll
            for (int q = 0; q < 8; ++q) {
                const int k = c * 32 + lk8 + q;
                r[q] = (__bf16)((k < KDIM) ? Wg[k * HDIM + hrow] : 0.f);
            }
            return r;
        }
    };

    f32x4 acc00 = {0,0,0,0}, acc01 = {0,0,0,0}, acc10 = {0,0,0,0}, acc11 = {0,0,0,0};

    bf16x8 aC0 = fragA(base0,      lin0);
    bf16x8 aC1 = fragA(base1,      lin1);
    bf16x8 aN0 = fragA(base0 + 64, lin0 + 32);
    bf16x8 aN1 = fragA(base1 + 64, lin1 + 32);
    #pragma unroll
    for (int c = 0; c < NCH; ++c) {
        bf16x8 aF0, aF1;
        if (c + 2 < NCH) {
            aF0 = fragA(base0 + 64 * (c + 2), lin0 + 32 * (c + 2));
            aF1 = fragA(base1 + 64 * (c + 2), lin1 + 32 * (c + 2));
        }
        bf16x8 w0 = fragW1(c, l15), w1 = fragW1(c, 16 + l15);
        acc00 = MFMA(aC0, w0, acc00);
        acc01 = MFMA(aC0, w1, acc01);
        acc10 = MFMA(aC1, w0, acc10);
        acc11 = MFMA(aC1, w1, acc11);
        aC0 = aN0; aC1 = aN1; aN0 = aF0; aN1 = aF1;
    }

    // ---- bias+relu -> h1 (wave-local LDS transpose, no barrier) ----
    constexpr int LDA = 40;
    #pragma unroll
    for (int r = 0; r < 4; ++r) {
        float v;
        v = acc00[r] + b1v0; h1s[(mrow +      r0 + r)*LDA +      l15] = (__bf16)(v > 0.f ? v : 0.f);
        v = acc01[r] + b1v1; h1s[(mrow +      r0 + r)*LDA + 16 + l15] = (__bf16)(v > 0.f ? v : 0.f);
        v = acc10[r] + b1v0; h1s[(mrow + 16 + r0 + r)*LDA +      l15] = (__bf16)(v > 0.f ? v : 0.f);
        v = acc11[r] + b1v1; h1s[(mrow + 16 + r0 + r)*LDA + 16 + l15] = (__bf16)(v > 0.f ? v : 0.f);
    }

    // ---------------- layer 2 ----------------
    const f32x4 z = {0,0,0,0};
    f32x4 c200, c201, c210, c211;
    {
        bf16x8 ha0 = *(const bf16x8*)&h1s[(mrow +      l15)*LDA + lk8];
        bf16x8 ha1 = *(const bf16x8*)&h1s[(mrow + 16 + l15)*LDA + lk8];
        c200 = MFMA(ha0, w2a, z); c201 = MFMA(ha0, w2b, z);
        c210 = MFMA(ha1, w2a, z); c211 = MFMA(ha1, w2b, z);
    }
    #pragma unroll
    for (int r = 0; r < 4; ++r) {
        float v;
        v = c200[r] + b2v0; h1s[(mrow +      r0 + r)*LDA +      l15] = (__bf16)(v > 0.f ? v : 0.f);
        v = c201[r] + b2v1; h1s[(mrow +      r0 + r)*LDA + 16 + l15] = (__bf16)(v > 0.f ? v : 0.f);
        v = c210[r] + b2v0; h1s[(mrow + 16 + r0 + r)*LDA +      l15] = (__bf16)(v > 0.f ? v : 0.f);
        v = c211[r] + b2v1; h1s[(mrow + 16 + r0 + r)*LDA + 16 + l15] = (__bf16)(v > 0.f ? v : 0.f);
    }

    // ---------------- layer 3 ----------------
    f32x4 c300, c301, c310, c311;
    {
        bf16x8 ha0 = *(const bf16x8*)&h1s[(mrow +      l15)*LDA + lk8];
        bf16x8 ha1 = *(const bf16x8*)&h1s[(mrow + 16 + l15)*LDA + lk8];
        c300 = MFMA(ha0, w3a, z); c301 = MFMA(ha0, w3b, z);
        c310 = MFMA(ha1, w3a, z); c311 = MFMA(ha1, w3b, z);
    }

    // ---------------- output ----------------
    const size_t orow = (size_t)(fi * BSZ + b0 + mrow);
    #pragma unroll
    for (int r = 0; r < 4; ++r) {
        float v;
        v = c300[r] + b3v0; out[(orow +      r0 + r)*HDIM +      l15] = v > 0.f ? v : 0.f;
        v = c301[r] + b3v1; out[(orow +      r0 + r)*HDIM + 16 + l15] = v > 0.f ? v : 0.f;
        v = c310[r] + b3v0; out[(orow + 16 + r0 + r)*HDIM +      l15] = v > 0.f ? v : 0.f;
        v = c311[r] + b3v1; out[(orow + 16 + r0 + r)*HDIM + 16 + l15] = v > 0.f ? v : 0.f;
    }
}

} // namespace

extern "C" void kernel_launch(void* const* d_in, const int* in_sizes, int n_in,
                              void* d_out, int out_size, void* d_ws, size_t ws_size,
                              hipStream_t stream) {
    const float* x  = (const float*)d_in[0];
    const float* W1 = (const float*)d_in[1];
    const float* b1 = (const float*)d_in[2];
    const float* W2 = (const float*)d_in[3];
    const float* b2 = (const float*)d_in[4];
    const float* W3 = (const float*)d_in[5];
    const float* b3 = (const float*)d_in[6];
    float* out = (float*)d_out;
    char* ws = (char*)d_ws;

    const bool fast = (ws != nullptr) && (ws_size >= WS_NEED);
    if (fast) {
        hipLaunchKernelGGL(cvt_all, dim3(CVT_BLK), dim3(256), 0, stream, x, W1, W2, W3, ws);
        hipLaunchKernelGGL((sfp3<true>), dim3(8 * 39 * 16), dim3(256), 0, stream,
                           x, W1, b1, W2, b2, W3, b3, ws, out);
    } else {
        hipLaunchKernelGGL((sfp3<false>), dim3(F_FEAT * 16), dim3(256), 0, stream,
                           x, W1, b1, W2, b2, W3, b3, ws, out);
    }
}